// Round 11
// baseline (2402.855 us; speedup 1.0000x reference)
//
#include <hip/hip_runtime.h>
#include <cstdio>
#include <cstdint>

constexpr int N_NODES = 20000;
constexpr int E_EDGES = 640000;
constexpr int S_STORIES = 32;
constexpr int G_TOT = 33;          // graph 0 = persona, 1..32 = stories
constexpr int IN_DIM = 384;
constexpr int HID = 128;
constexpr int F_OUT = 64;
constexpr float NEG_SLOPE = 0.2f;

// CSR build geometry
constexpr int EPB = 8192;
constexpr int NB = (E_EDGES + EPB - 1) / EPB;      // 79
constexpr int NBUCK = (N_NODES + 63) / 64;         // 313

typedef short short8 __attribute__((ext_vector_type(8)));
typedef float f32x4 __attribute__((ext_vector_type(4)));
typedef float f32x2 __attribute__((ext_vector_type(2)));

__device__ __forceinline__ float leaky(float x) { return x > 0.f ? x : NEG_SLOPE * x; }

// bf16 pack/unpack (RNE)
__device__ __forceinline__ uint32_t f2bf(float x) {
    uint32_t u = __builtin_bit_cast(uint32_t, x);
    return (u + 0x7fffu + ((u >> 16) & 1u)) >> 16;
}
__device__ __forceinline__ uint32_t pk2(float lo, float hi) { return (f2bf(hi) << 16) | f2bf(lo); }
__device__ __forceinline__ float bflo(uint32_t u) { return __builtin_bit_cast(float, u << 16); }
__device__ __forceinline__ float bfhi(uint32_t u) { return __builtin_bit_cast(float, u & 0xffff0000u); }

// fp8 e4m3 (HW path, self-consistent encode/decode)
__device__ __forceinline__ uint8_t f2fp8(float v) {
    return (uint8_t)__builtin_amdgcn_cvt_pk_fp8_f32(v, v, 0, false);
}

// ---------- zero emb ----------
__global__ void zero_kernel(float* __restrict__ b, size_t nb) {
    size_t i = (size_t)blockIdx.x * blockDim.x + threadIdx.x;
    if (i < nb) b[i] = 0.f;
}

// ---------- CSR phase A ----------
__global__ __launch_bounds__(256) void csr_count(const int* __restrict__ pei, const int* __restrict__ sei,
                                                 unsigned* __restrict__ C) {
    int blk = blockIdx.x;
    int g = blk / NB, k = blk - g * NB;
    const int* ei = (g == 0) ? pei : sei + (size_t)(g - 1) * 2 * E_EDGES;
    const int* dstp = ei + E_EDGES;
    int lo = k * EPB, hi = min(lo + EPB, E_EDGES);
    __shared__ unsigned cnt[NBUCK];
    for (int i = threadIdx.x; i < NBUCK; i += 256) cnt[i] = 0;
    __syncthreads();
    for (int i = lo + threadIdx.x; i < hi; i += 256)
        atomicAdd(&cnt[dstp[i] >> 6], 1u);
    __syncthreads();
    unsigned* Cb = C + ((size_t)g * NB + k) * NBUCK;
    for (int i = threadIdx.x; i < NBUCK; i += 256) Cb[i] = cnt[i];
}

// ---------- CSR phase B ----------
__global__ __launch_bounds__(512) void csr_scan(unsigned* __restrict__ C, unsigned* __restrict__ BB) {
    int g = blockIdx.x;
    __shared__ unsigned tot[NBUCK + 1];
    unsigned* Cg = C + (size_t)g * NB * NBUCK;
    for (int b = threadIdx.x; b < NBUCK; b += 512) {
        unsigned s = 0;
        for (int k = 0; k < NB; ++k) s += Cg[(size_t)k * NBUCK + b];
        tot[b] = s;
    }
    __syncthreads();
    if (threadIdx.x == 0) {
        unsigned run = 0;
        for (int b = 0; b < NBUCK; ++b) { unsigned t = tot[b]; tot[b] = run; run += t; }
        tot[NBUCK] = run;
    }
    __syncthreads();
    for (int b = threadIdx.x; b <= NBUCK; b += 512) BB[(size_t)g * (NBUCK + 1) + b] = tot[b];
    for (int b = threadIdx.x; b < NBUCK; b += 512) {
        unsigned run = tot[b];
        for (int k = 0; k < NB; ++k) {
            unsigned t = Cg[(size_t)k * NBUCK + b];
            Cg[(size_t)k * NBUCK + b] = run;
            run += t;
        }
    }
}

// ---------- CSR phase C ----------
__global__ __launch_bounds__(256) void csr_bucket(const int* __restrict__ pei, const int* __restrict__ sei,
                                                  const unsigned* __restrict__ C, unsigned* __restrict__ tmp) {
    int blk = blockIdx.x;
    int g = blk / NB, k = blk - g * NB;
    const int* ei = (g == 0) ? pei : sei + (size_t)(g - 1) * 2 * E_EDGES;
    int lo = k * EPB, hi = min(lo + EPB, E_EDGES);
    __shared__ unsigned off[NBUCK];
    const unsigned* Cb = C + ((size_t)g * NB + k) * NBUCK;
    for (int i = threadIdx.x; i < NBUCK; i += 256) off[i] = Cb[i];
    __syncthreads();
    unsigned* tg = tmp + (size_t)g * E_EDGES;
    for (int i = lo + threadIdx.x; i < hi; i += 256) {
        int s = ei[i], d = ei[E_EDGES + i];
        unsigned r = atomicAdd(&off[d >> 6], 1u);
        tg[r] = ((unsigned)(d & 63) << 15) | (unsigned)s;
    }
}

// ---------- CSR phase D ----------
__global__ __launch_bounds__(256) void csr_fine(const unsigned* __restrict__ tmp, const unsigned* __restrict__ BB,
                                                int* __restrict__ row, int* __restrict__ csr_src) {
    int blk = blockIdx.x;
    int g = blk / NBUCK, b = blk - g * NBUCK;
    unsigned lo = BB[(size_t)g * (NBUCK + 1) + b];
    unsigned hi = BB[(size_t)g * (NBUCK + 1) + b + 1];
    __shared__ unsigned cnt[64];
    __shared__ unsigned pos[64];
    if (threadIdx.x < 64) cnt[threadIdx.x] = 0;
    __syncthreads();
    const unsigned* tg = tmp + (size_t)g * E_EDGES;
    for (unsigned i = lo + threadIdx.x; i < hi; i += 256)
        atomicAdd(&cnt[(tg[i] >> 15) & 63], 1u);
    __syncthreads();
    if (threadIdx.x < 64) {
        unsigned v = cnt[threadIdx.x];
        unsigned inc = v;
#pragma unroll
        for (int o = 1; o < 64; o <<= 1) {
            unsigned u = __shfl_up(inc, o);
            if ((int)threadIdx.x >= o) inc += u;
        }
        unsigned e = inc - v;
        pos[threadIdx.x] = lo + e;
        int n = b * 64 + (int)threadIdx.x;
        if (n <= N_NODES) row[(size_t)g * (N_NODES + 1) + n] = (int)(lo + e);
    }
    __syncthreads();
    for (unsigned i = lo + threadIdx.x; i < hi; i += 256) {
        unsigned v = tg[i];
        unsigned r = atomicAdd(&pos[(v >> 15) & 63], 1u);
        csr_src[(size_t)g * E_EDGES + r] = (int)(v & 0x7fffu);
    }
}

// ---------- W prep: transpose + bf16 hi/lo split. Layout: [plane][type][col][K] ----------
__global__ void wprep_kernel(const float* __restrict__ pW1, const float* __restrict__ sW1,
                             const float* __restrict__ pW2, const float* __restrict__ sW2,
                             short* __restrict__ w1t, short* __restrict__ w2t) {
    constexpr int N1 = 2 * HID * IN_DIM;
    constexpr int N2 = 2 * F_OUT * HID;
    int idx = blockIdx.x * 256 + threadIdx.x;
    if (idx < N1) {
        int t = idx / (HID * IN_DIM);
        int r = idx % (HID * IN_DIM);
        int col = r / IN_DIM, k = r % IN_DIM;
        const float* W = t ? sW1 : pW1;
        float v = W[(size_t)k * HID + col];
        uint32_t hi = f2bf(v);
        float fhi = __builtin_bit_cast(float, hi << 16);
        w1t[idx]      = (short)hi;
        w1t[idx + N1] = (short)f2bf(v - fhi);
    } else if (idx < N1 + N2) {
        int j = idx - N1;
        int t = j / (F_OUT * HID);
        int r = j % (F_OUT * HID);
        int col = r / HID, k = r % HID;
        const float* W = t ? sW2 : pW2;
        float v = W[(size_t)k * F_OUT + col];
        uint32_t hi = f2bf(v);
        float fhi = __builtin_bit_cast(float, hi << 16);
        w2t[j]      = (short)hi;
        w2t[j + N2] = (short)f2bf(v - fhi);
    }
}

// ---------- MFMA GEMM: bf16 out + fp8 shadow copy ----------
template<int KDIM, int NCOL, bool CVT>
__global__ __launch_bounds__(256) void mm_mfma(const void* __restrict__ pXv, const void* __restrict__ sXv,
                                               const short* __restrict__ wt,   // [2 planes][2 types][NCOL][KDIM]
                                               uint16_t* __restrict__ outb, uint8_t* __restrict__ out8) {
    constexpr int BPG = (N_NODES + 127) / 128;   // 157
    constexpr int NT = NCOL / 16;
    int g = blockIdx.x / BPG;
    int brow = (blockIdx.x % BPG) * 128;
    const short* wtg = wt + (g ? (size_t)NCOL * KDIM : 0);   // hi plane; lo at +2*NCOL*KDIM
    __shared__ __align__(16) short As[128 * 40];
    __shared__ __align__(16) short Bh[NCOL * 40];
    __shared__ __align__(16) short Bl[NCOL * 40];
    int tid = threadIdx.x;
    int w = tid >> 6, l = tid & 63;
    int lr = l & 15, kq = l >> 4;
    f32x4 acc[2][NT] = {};
    for (int k0 = 0; k0 < KDIM; k0 += 32) {
        if (CVT) {
            const float* X = (g == 0) ? (const float*)pXv
                                      : (const float*)sXv + (size_t)(g - 1) * N_NODES * KDIM;
#pragma unroll
            for (int i = 0; i < 4; ++i) {                 // 128 rows x 8 float4 = 1024 transactions
                int v = tid + i * 256;
                int r = v >> 3, q = v & 7;
                float4 xv = make_float4(0.f, 0.f, 0.f, 0.f);
                if (brow + r < N_NODES)
                    xv = *(const float4*)(X + (size_t)(brow + r) * KDIM + k0 + q * 4);
                uint2 pkd; pkd.x = pk2(xv.x, xv.y); pkd.y = pk2(xv.z, xv.w);
                *(uint2*)(As + r * 40 + q * 4) = pkd;
            }
        } else {
            const uint16_t* X = (g == 0) ? (const uint16_t*)pXv
                                         : (const uint16_t*)sXv + (size_t)(g - 1) * N_NODES * KDIM;
#pragma unroll
            for (int i = 0; i < 2; ++i) {                 // 128 rows x 4 uint4 = 512 transactions
                int v = tid + i * 256;
                int r = v >> 2, q = v & 3;
                uint4 xv = make_uint4(0u, 0u, 0u, 0u);
                if (brow + r < N_NODES)
                    xv = *(const uint4*)(X + (size_t)(brow + r) * KDIM + k0 + q * 8);
                *(uint4*)(As + r * 40 + q * 8) = xv;
            }
        }
        for (int v = tid; v < NCOL * 4; v += 256) {       // B: NCOL rows x 4 uint4, hi+lo
            int r = v >> 2, q = v & 3;
            const short* srcp = wtg + (size_t)r * KDIM + k0 + q * 8;
            *(uint4*)(Bh + r * 40 + q * 8) = *(const uint4*)srcp;
            *(uint4*)(Bl + r * 40 + q * 8) = *(const uint4*)(srcp + (size_t)2 * NCOL * KDIM);
        }
        __syncthreads();
        short8 a0 = *(const short8*)(As + (w * 32 + lr) * 40 + kq * 8);
        short8 a1 = *(const short8*)(As + (w * 32 + 16 + lr) * 40 + kq * 8);
#pragma unroll
        for (int ct = 0; ct < NT; ++ct) {
            short8 bh = *(const short8*)(Bh + (ct * 16 + lr) * 40 + kq * 8);
            short8 bl = *(const short8*)(Bl + (ct * 16 + lr) * 40 + kq * 8);
            acc[0][ct] = __builtin_amdgcn_mfma_f32_16x16x32_bf16(a0, bh, acc[0][ct], 0, 0, 0);
            acc[0][ct] = __builtin_amdgcn_mfma_f32_16x16x32_bf16(a0, bl, acc[0][ct], 0, 0, 0);
            acc[1][ct] = __builtin_amdgcn_mfma_f32_16x16x32_bf16(a1, bh, acc[1][ct], 0, 0, 0);
            acc[1][ct] = __builtin_amdgcn_mfma_f32_16x16x32_bf16(a1, bl, acc[1][ct], 0, 0, 0);
        }
        __syncthreads();
    }
#pragma unroll
    for (int rt = 0; rt < 2; ++rt) {
#pragma unroll
        for (int ct = 0; ct < NT; ++ct) {
#pragma unroll
            for (int i = 0; i < 4; ++i) {
                int node = brow + w * 32 + rt * 16 + kq * 4 + i;
                if (node < N_NODES) {
                    float v = acc[rt][ct][i];
                    size_t o = (size_t)g * N_NODES + node;
                    outb[o * NCOL + ct * 16 + lr] = (uint16_t)f2bf(v);
                    out8[o * NCOL + ct * 16 + lr] = f2fp8(v);
                }
            }
        }
    }
}

// ---------- per-node attention scalars from bf16 h ----------
__global__ __launch_bounds__(256) void asad128_kernel(const uint32_t* __restrict__ hb,
                                                      const float* __restrict__ pa, const float* __restrict__ sa,
                                                      float* __restrict__ as_, float* __restrict__ ad_) {
    int wid = (blockIdx.x * 256 + threadIdx.x) >> 6;
    int lane = threadIdx.x & 63;
    if (wid >= G_TOT * N_NODES) return;
    int g = wid / N_NODES;
    const float* a = (g == 0) ? pa : sa;
    uint32_t hv = hb[(size_t)wid * 64 + lane];
    float h0 = bflo(hv), h1 = bfhi(hv);
    float2 a_s = *(const float2*)(a + 2 * lane);
    float2 a_d = *(const float2*)(a + 128 + 2 * lane);
    float s = h0 * a_s.x + h1 * a_s.y;
    float d = h0 * a_d.x + h1 * a_d.y;
#pragma unroll
    for (int off = 32; off; off >>= 1) { s += __shfl_xor(s, off); d += __shfl_xor(d, off); }
    if (lane == 0) { as_[wid] = s; ad_[wid] = d; }
}

__global__ __launch_bounds__(256) void asad64_kernel(const uint32_t* __restrict__ hb,
                                                     const float* __restrict__ pa, const float* __restrict__ sa,
                                                     float* __restrict__ as_, float* __restrict__ ad_) {
    int wid = (blockIdx.x * 256 + threadIdx.x) >> 6;
    int lane = threadIdx.x & 63;
    if (wid >= G_TOT * N_NODES) return;
    int g = wid / N_NODES;
    const float* a = (g == 0) ? pa : sa;
    const uint16_t* hr = (const uint16_t*)(hb + (size_t)wid * 32);
    float h = __builtin_bit_cast(float, (uint32_t)hr[lane] << 16);
    float s = h * a[lane];
    float d = h * a[64 + lane];
#pragma unroll
    for (int off = 32; off; off >>= 1) { s += __shfl_xor(s, off); d += __shfl_xor(d, off); }
    if (lane == 0) { as_[wid] = s; ad_[wid] = d; }
}

// ---------- GAT aggregation, F=128: online softmax + fp8 4-edge/16-lane gather; self bf16; bf16 out ----------
__global__ __launch_bounds__(256) void agg128_kernel(const uint32_t* __restrict__ hb,
                                                     const uint32_t* __restrict__ h8,
                                                     const float* __restrict__ as_, const float* __restrict__ ad_,
                                                     const int* __restrict__ row, const int* __restrict__ csr_src,
                                                     const float* __restrict__ pb, const float* __restrict__ sb,
                                                     uint32_t* __restrict__ h1p) {
    int node = blockIdx.x * 4 + (threadIdx.x >> 6);
    int g = node / N_NODES;
    int n = node - g * N_NODES;
    int lane = threadIdx.x & 63;
    int start = row[(size_t)g * (N_NODES + 1) + n];
    int end   = row[(size_t)g * (N_NODES + 1) + n + 1];
    const int* src = csr_src + (size_t)g * E_EDGES;
    const float* asg = as_ + (size_t)g * N_NODES;
    const uint32_t* hg  = hb + (size_t)g * N_NODES * 64;   // bf16 rows (self)
    const uint32_t* h8g = h8 + (size_t)g * N_NODES * 32;   // fp8 rows (gather), 32 u32 = 128 B
    float ad_d = ad_[node];
    float e_self = leaky(asg[n] + ad_d);
    int grp = lane >> 4;                 // edge slot within quad
    int f = lane & 15;                   // feats f*8 .. f*8+7
    const uint32_t* hf = h8g + f * 2;
    float m = e_self, denomp = 0.f;
    float a0 = 0.f, a1 = 0.f, a2 = 0.f, a3 = 0.f, a4 = 0.f, a5 = 0.f, a6 = 0.f, a7 = 0.f;
    for (int j0 = start; j0 < end; j0 += 64) {
        int j = j0 + lane;
        float e = -3.0e38f; int s0 = 0;
        if (j < end) { s0 = src[j]; e = leaky(asg[s0] + ad_d); }
        float cmax = e;
#pragma unroll
        for (int off = 32; off; off >>= 1) cmax = fmaxf(cmax, __shfl_xor(cmax, off));
        if (cmax > m) {                  // wave-uniform rescale (rare)
            float sc = __expf(m - cmax);
            denomp *= sc;
            a0 *= sc; a1 *= sc; a2 *= sc; a3 *= sc; a4 *= sc; a5 *= sc; a6 *= sc; a7 *= sc;
            m = cmax;
        }
        float w0 = (j < end) ? __expf(e - m) : 0.f;
        denomp += w0;
        int cnt = min(64, end - j0);
        for (int t = 0; t < cnt; t += 4) {
            int tt = t + grp;            // <= 63 always; w0[tt]=0 for tail
            float w = __shfl(w0, tt);
            int   s = __shfl(s0, tt);
            uint2 hv = *(const uint2*)(hf + (size_t)s * 32);
            f32x2 p0 = __builtin_amdgcn_cvt_pk_f32_fp8(hv.x, false);
            f32x2 p1 = __builtin_amdgcn_cvt_pk_f32_fp8(hv.x, true);
            f32x2 p2 = __builtin_amdgcn_cvt_pk_f32_fp8(hv.y, false);
            f32x2 p3 = __builtin_amdgcn_cvt_pk_f32_fp8(hv.y, true);
            a0 += w * p0.x; a1 += w * p0.y;
            a2 += w * p1.x; a3 += w * p1.y;
            a4 += w * p2.x; a5 += w * p2.y;
            a6 += w * p3.x; a7 += w * p3.y;
        }
    }
#pragma unroll
    for (int off = 32; off; off >>= 1) denomp += __shfl_xor(denomp, off);
#pragma unroll
    for (int off = 16; off <= 32; off <<= 1) {
        a0 += __shfl_xor(a0, off); a1 += __shfl_xor(a1, off);
        a2 += __shfl_xor(a2, off); a3 += __shfl_xor(a3, off);
        a4 += __shfl_xor(a4, off); a5 += __shfl_xor(a5, off);
        a6 += __shfl_xor(a6, off); a7 += __shfl_xor(a7, off);
    }
    if (lane < 16) {
        float wself = __expf(e_self - m);
        float inv = 1.f / (denomp + wself + 1e-16f);
        uint4 hv = *(const uint4*)(hg + (size_t)n * 64 + lane * 4);   // self row: bf16 precision
        const float* b = (g == 0) ? pb : sb;
        float4 b0 = *(const float4*)(b + lane * 8);
        float4 b1 = *(const float4*)(b + lane * 8 + 4);
        float o0 = fmaxf((a0 + wself * bflo(hv.x)) * inv + b0.x, 0.f);
        float o1 = fmaxf((a1 + wself * bfhi(hv.x)) * inv + b0.y, 0.f);
        float o2 = fmaxf((a2 + wself * bflo(hv.y)) * inv + b0.z, 0.f);
        float o3 = fmaxf((a3 + wself * bfhi(hv.y)) * inv + b0.w, 0.f);
        float o4 = fmaxf((a4 + wself * bflo(hv.z)) * inv + b1.x, 0.f);
        float o5 = fmaxf((a5 + wself * bfhi(hv.z)) * inv + b1.y, 0.f);
        float o6 = fmaxf((a6 + wself * bflo(hv.w)) * inv + b1.z, 0.f);
        float o7 = fmaxf((a7 + wself * bfhi(hv.w)) * inv + b1.w, 0.f);
        uint4 o; o.x = pk2(o0, o1); o.y = pk2(o2, o3); o.z = pk2(o4, o5); o.w = pk2(o6, o7);
        *(uint4*)(h1p + (size_t)node * 64 + lane * 4) = o;
    }
}

// ---------- GAT aggregation, F=64: online softmax + fp8 4-edge/16-lane gather; self bf16; bf16 out ----------
__global__ __launch_bounds__(256) void agg64_kernel(const uint32_t* __restrict__ hb,
                                                    const uint32_t* __restrict__ h8,
                                                    const float* __restrict__ as_, const float* __restrict__ ad_,
                                                    const int* __restrict__ row, const int* __restrict__ csr_src,
                                                    const float* __restrict__ pb, const float* __restrict__ sb,
                                                    uint32_t* __restrict__ out2b) {
    int node = blockIdx.x * 4 + (threadIdx.x >> 6);
    int g = node / N_NODES;
    int n = node - g * N_NODES;
    int lane = threadIdx.x & 63;
    int start = row[(size_t)g * (N_NODES + 1) + n];
    int end   = row[(size_t)g * (N_NODES + 1) + n + 1];
    const int* src = csr_src + (size_t)g * E_EDGES;
    const float* asg = as_ + (size_t)g * N_NODES;
    const uint32_t* hg  = hb + (size_t)g * N_NODES * 32;   // bf16 rows (self)
    const uint32_t* h8g = h8 + (size_t)g * N_NODES * 16;   // fp8 rows (gather), 16 u32 = 64 B
    float ad_d = ad_[node];
    float e_self = leaky(asg[n] + ad_d);
    int grp = lane >> 4;
    int f = lane & 15;                   // feats f*4 .. f*4+3
    const uint32_t* hf = h8g + f;
    float m = e_self, denomp = 0.f;
    float a0 = 0.f, a1 = 0.f, a2 = 0.f, a3 = 0.f;
    for (int j0 = start; j0 < end; j0 += 64) {
        int j = j0 + lane;
        float e = -3.0e38f; int s0 = 0;
        if (j < end) { s0 = src[j]; e = leaky(asg[s0] + ad_d); }
        float cmax = e;
#pragma unroll
        for (int off = 32; off; off >>= 1) cmax = fmaxf(cmax, __shfl_xor(cmax, off));
        if (cmax > m) {
            float sc = __expf(m - cmax);
            denomp *= sc;
            a0 *= sc; a1 *= sc; a2 *= sc; a3 *= sc;
            m = cmax;
        }
        float w0 = (j < end) ? __expf(e - m) : 0.f;
        denomp += w0;
        int cnt = min(64, end - j0);
        for (int t = 0; t < cnt; t += 4) {
            int tt = t + grp;
            float w = __shfl(w0, tt);
            int   s = __shfl(s0, tt);
            uint32_t hv = hf[(size_t)s * 16];
            f32x2 p0 = __builtin_amdgcn_cvt_pk_f32_fp8(hv, false);
            f32x2 p1 = __builtin_amdgcn_cvt_pk_f32_fp8(hv, true);
            a0 += w * p0.x; a1 += w * p0.y;
            a2 += w * p1.x; a3 += w * p1.y;
        }
    }
#pragma unroll
    for (int off = 32; off; off >>= 1) denomp += __shfl_xor(denomp, off);
#pragma unroll
    for (int off = 16; off <= 32; off <<= 1) {
        a0 += __shfl_xor(a0, off); a1 += __shfl_xor(a1, off);
        a2 += __shfl_xor(a2, off); a3 += __shfl_xor(a3, off);
    }
    if (lane < 16) {
        float wself = __expf(e_self - m);
        float inv = 1.f / (denomp + wself + 1e-16f);
        uint2 hv = *(const uint2*)(hg + (size_t)n * 32 + lane * 2);   // self row: bf16
        const float* b = (g == 0) ? pb : sb;
        float4 bv = *(const float4*)(b + lane * 4);
        float o0 = (a0 + wself * bflo(hv.x)) * inv + bv.x;
        float o1 = (a1 + wself * bfhi(hv.x)) * inv + bv.y;
        float o2 = (a2 + wself * bflo(hv.y)) * inv + bv.z;
        float o3 = (a3 + wself * bfhi(hv.y)) * inv + bv.w;
        uint2 o; o.x = pk2(o0, o1); o.y = pk2(o2, o3);
        *(uint2*)(out2b + (size_t)node * 32 + lane * 2) = o;
    }
}

// ---------- mean over nodes (bf16 in) -> emb[g][64] ----------
__global__ __launch_bounds__(256) void mean_kernel(const uint32_t* __restrict__ out2b, float* __restrict__ emb) {
    constexpr int CH = 32;
    int g = blockIdx.x / CH, chunk = blockIdx.x % CH;
    int sub = threadIdx.x >> 5;          // 8 node groups
    int q = threadIdx.x & 31;            // uint32 idx: feats 2q, 2q+1
    const uint32_t* og = out2b + (size_t)g * N_NODES * 32;
    float a0 = 0.f, a1 = 0.f;
    for (int n = chunk * 8 + sub; n < N_NODES; n += CH * 8) {
        uint32_t v = og[(size_t)n * 32 + q];
        a0 += bflo(v); a1 += bfhi(v);
    }
    __shared__ float red[256][2];
    red[threadIdx.x][0] = a0; red[threadIdx.x][1] = a1;
    __syncthreads();
    if (sub == 0) {
        float s0 = 0.f, s1 = 0.f;
        for (int k = 0; k < 8; ++k) { s0 += red[k * 32 + q][0]; s1 += red[k * 32 + q][1]; }
        atomicAdd(&emb[g * 64 + 2 * q],     s0 * (1.f / N_NODES));
        atomicAdd(&emb[g * 64 + 2 * q + 1], s1 * (1.f / N_NODES));
    }
}

// ---------- cosine-similarity head ----------
__global__ __launch_bounds__(64) void final_kernel(const float* __restrict__ emb,
                                                   const float* __restrict__ temp, float* __restrict__ out) {
    int lane = threadIdx.x;
    float pe = emb[lane];
    float pp = pe * pe;
#pragma unroll
    for (int off = 32; off; off >>= 1) pp += __shfl_xor(pp, off);
    float t = temp[0];
    float pn = sqrtf(pp);
    for (int s_i = 0; s_i < S_STORIES; ++s_i) {
        float se = emb[(1 + s_i) * 64 + lane];
        float ss = se * se;
        float dt = se * pe;
#pragma unroll
        for (int off = 32; off; off >>= 1) { ss += __shfl_xor(ss, off); dt += __shfl_xor(dt, off); }
        if (lane == 0) out[s_i] = dt / (sqrtf(ss) * pn * t);
    }
}

extern "C" void kernel_launch(void* const* d_in, const int* in_sizes, int n_in,
                              void* d_out, int out_size, void* d_ws, size_t ws_size,
                              hipStream_t stream) {
    const float* persona_x = (const float*)d_in[0];
    const int*   pei       = (const int*)d_in[1];
    const float* story_x   = (const float*)d_in[2];
    const int*   sei       = (const int*)d_in[3];
    const float* p_W1 = (const float*)d_in[4];
    const float* p_a1 = (const float*)d_in[5];
    const float* p_b1 = (const float*)d_in[6];
    const float* p_W2 = (const float*)d_in[7];
    const float* p_a2 = (const float*)d_in[8];
    const float* p_b2 = (const float*)d_in[9];
    const float* s_W1 = (const float*)d_in[10];
    const float* s_a1 = (const float*)d_in[11];
    const float* s_b1 = (const float*)d_in[12];
    const float* s_W2 = (const float*)d_in[13];
    const float* s_a2 = (const float*)d_in[14];
    const float* s_b2 = (const float*)d_in[15];
    const float* temp = (const float*)d_in[16];
    float* out = (float*)d_out;

    char* ws = (char*)d_ws;
    size_t off = 0;
    auto alloc = [&](size_t bytes) { char* p = ws + off; off += (bytes + 255) & ~(size_t)255; return p; };
    uint32_t* hb1  = (uint32_t*)alloc((size_t)G_TOT * N_NODES * 64 * 4);   // bf16 h1; CSR tmp + out2b alias
    uint32_t* h1p  = (uint32_t*)alloc((size_t)G_TOT * N_NODES * 64 * 4);   // bf16 h1'; CSR C/BB alias
    uint32_t* hb2  = (uint32_t*)alloc((size_t)G_TOT * N_NODES * 32 * 4);   // bf16 h2
    uint8_t*  h8_1 = (uint8_t*) alloc((size_t)G_TOT * N_NODES * 128);      // fp8 h1 (gather copy)
    uint8_t*  h8_2 = (uint8_t*) alloc((size_t)G_TOT * N_NODES * 64);       // fp8 h2 (gather copy)
    float* as_     = (float*)alloc((size_t)G_TOT * N_NODES * 4);
    float* ad_     = (float*)alloc((size_t)G_TOT * N_NODES * 4);
    int*   csr_row = (int*)  alloc((size_t)G_TOT * (N_NODES + 1) * 4);
    int*   csr_src = (int*)  alloc((size_t)G_TOT * E_EDGES * 4);
    float* emb     = (float*)alloc((size_t)G_TOT * 64 * 4);
    short* w1t     = (short*)alloc((size_t)2 * 2 * HID * IN_DIM * 2);      // [plane][type][col][K]
    short* w2t     = (short*)alloc((size_t)2 * 2 * F_OUT * HID * 2);
    if (off > ws_size) {
        fprintf(stderr, "kernel_launch: ws too small: need %zu have %zu\n", off, ws_size);
        return;
    }
    unsigned* tmp = (unsigned*)hb1;                                    // 84.5 MB <= 169 MB, dead before mm1
    unsigned* C   = (unsigned*)h1p;                                    // 3.3 MB, dead before agg128
    unsigned* BB  = (unsigned*)h1p + (size_t)G_TOT * NB * NBUCK;
    uint32_t* out2b = hb1;                                             // hb1 dead after agg128 (self-reads done)

    constexpr int BPG = (N_NODES + 127) / 128;   // 157
    const int NODE_BLOCKS = G_TOT * N_NODES / 4; // 165000, exact

    // CSR build + weight prep
    zero_kernel<<<(G_TOT * 64 + 255) / 256, 256, 0, stream>>>(emb, (size_t)G_TOT * 64);
    wprep_kernel<<<(2 * HID * IN_DIM + 2 * F_OUT * HID + 255) / 256, 256, 0, stream>>>(p_W1, s_W1, p_W2, s_W2, w1t, w2t);
    csr_count <<<G_TOT * NB, 256, 0, stream>>>(pei, sei, C);
    csr_scan  <<<G_TOT, 512, 0, stream>>>(C, BB);
    csr_bucket<<<G_TOT * NB, 256, 0, stream>>>(pei, sei, C, tmp);
    csr_fine  <<<G_TOT * NBUCK, 256, 0, stream>>>(tmp, BB, csr_row, csr_src);

    // Layer 1
    mm_mfma<IN_DIM, HID, true><<<G_TOT * BPG, 256, 0, stream>>>(persona_x, story_x, w1t, (uint16_t*)hb1, h8_1);
    asad128_kernel<<<(G_TOT * N_NODES + 3) / 4, 256, 0, stream>>>(hb1, p_a1, s_a1, as_, ad_);
    agg128_kernel<<<NODE_BLOCKS, 256, 0, stream>>>(hb1, (const uint32_t*)h8_1, as_, ad_, csr_row, csr_src, p_b1, s_b1, h1p);

    // Layer 2 (A operand already bf16)
    const uint16_t* h1p16 = (const uint16_t*)h1p;
    mm_mfma<HID, F_OUT, false><<<G_TOT * BPG, 256, 0, stream>>>(h1p16, h1p16 + (size_t)N_NODES * HID, w2t, (uint16_t*)hb2, h8_2);
    asad64_kernel<<<(G_TOT * N_NODES + 3) / 4, 256, 0, stream>>>(hb2, p_a2, s_a2, as_, ad_);
    agg64_kernel<<<NODE_BLOCKS, 256, 0, stream>>>(hb2, (const uint32_t*)h8_2, as_, ad_, csr_row, csr_src, p_b2, s_b2, out2b);

    // Readout
    mean_kernel<<<G_TOT * 32, 256, 0, stream>>>(out2b, emb);
    final_kernel<<<1, 64, 0, stream>>>(emb, temp, out);
}

// Round 12
// 2192.210 us; speedup vs baseline: 1.0961x; 1.0961x over previous
//
#include <hip/hip_runtime.h>
#include <cstdio>
#include <cstdint>

constexpr int N_NODES = 20000;
constexpr int E_EDGES = 640000;
constexpr int S_STORIES = 32;
constexpr int G_TOT = 33;          // graph 0 = persona, 1..32 = stories
constexpr int IN_DIM = 384;
constexpr int HID = 128;
constexpr int F_OUT = 64;
constexpr float NEG_SLOPE = 0.2f;

// CSR build geometry
constexpr int EPB = 8192;
constexpr int NB = (E_EDGES + EPB - 1) / EPB;      // 79
constexpr int NBUCK = (N_NODES + 63) / 64;         // 313

typedef short short8 __attribute__((ext_vector_type(8)));
typedef float f32x4 __attribute__((ext_vector_type(4)));

__device__ __forceinline__ float leaky(float x) { return x > 0.f ? x : NEG_SLOPE * x; }

// bf16 pack/unpack (RNE)
__device__ __forceinline__ uint32_t f2bf(float x) {
    uint32_t u = __builtin_bit_cast(uint32_t, x);
    return (u + 0x7fffu + ((u >> 16) & 1u)) >> 16;
}
__device__ __forceinline__ uint32_t pk2(float lo, float hi) { return (f2bf(hi) << 16) | f2bf(lo); }
__device__ __forceinline__ float bflo(uint32_t u) { return __builtin_bit_cast(float, u << 16); }
__device__ __forceinline__ float bfhi(uint32_t u) { return __builtin_bit_cast(float, u & 0xffff0000u); }

// ---------- zero emb ----------
__global__ void zero_kernel(float* __restrict__ b, size_t nb) {
    size_t i = (size_t)blockIdx.x * blockDim.x + threadIdx.x;
    if (i < nb) b[i] = 0.f;
}

// ---------- CSR phase A ----------
__global__ __launch_bounds__(256) void csr_count(const int* __restrict__ pei, const int* __restrict__ sei,
                                                 unsigned* __restrict__ C) {
    int blk = blockIdx.x;
    int g = blk / NB, k = blk - g * NB;
    const int* ei = (g == 0) ? pei : sei + (size_t)(g - 1) * 2 * E_EDGES;
    const int* dstp = ei + E_EDGES;
    int lo = k * EPB, hi = min(lo + EPB, E_EDGES);
    __shared__ unsigned cnt[NBUCK];
    for (int i = threadIdx.x; i < NBUCK; i += 256) cnt[i] = 0;
    __syncthreads();
    for (int i = lo + threadIdx.x; i < hi; i += 256)
        atomicAdd(&cnt[dstp[i] >> 6], 1u);
    __syncthreads();
    unsigned* Cb = C + ((size_t)g * NB + k) * NBUCK;
    for (int i = threadIdx.x; i < NBUCK; i += 256) Cb[i] = cnt[i];
}

// ---------- CSR phase B ----------
__global__ __launch_bounds__(512) void csr_scan(unsigned* __restrict__ C, unsigned* __restrict__ BB) {
    int g = blockIdx.x;
    __shared__ unsigned tot[NBUCK + 1];
    unsigned* Cg = C + (size_t)g * NB * NBUCK;
    for (int b = threadIdx.x; b < NBUCK; b += 512) {
        unsigned s = 0;
        for (int k = 0; k < NB; ++k) s += Cg[(size_t)k * NBUCK + b];
        tot[b] = s;
    }
    __syncthreads();
    if (threadIdx.x == 0) {
        unsigned run = 0;
        for (int b = 0; b < NBUCK; ++b) { unsigned t = tot[b]; tot[b] = run; run += t; }
        tot[NBUCK] = run;
    }
    __syncthreads();
    for (int b = threadIdx.x; b <= NBUCK; b += 512) BB[(size_t)g * (NBUCK + 1) + b] = tot[b];
    for (int b = threadIdx.x; b < NBUCK; b += 512) {
        unsigned run = tot[b];
        for (int k = 0; k < NB; ++k) {
            unsigned t = Cg[(size_t)k * NBUCK + b];
            Cg[(size_t)k * NBUCK + b] = run;
            run += t;
        }
    }
}

// ---------- CSR phase C ----------
__global__ __launch_bounds__(256) void csr_bucket(const int* __restrict__ pei, const int* __restrict__ sei,
                                                  const unsigned* __restrict__ C, unsigned* __restrict__ tmp) {
    int blk = blockIdx.x;
    int g = blk / NB, k = blk - g * NB;
    const int* ei = (g == 0) ? pei : sei + (size_t)(g - 1) * 2 * E_EDGES;
    int lo = k * EPB, hi = min(lo + EPB, E_EDGES);
    __shared__ unsigned off[NBUCK];
    const unsigned* Cb = C + ((size_t)g * NB + k) * NBUCK;
    for (int i = threadIdx.x; i < NBUCK; i += 256) off[i] = Cb[i];
    __syncthreads();
    unsigned* tg = tmp + (size_t)g * E_EDGES;
    for (int i = lo + threadIdx.x; i < hi; i += 256) {
        int s = ei[i], d = ei[E_EDGES + i];
        unsigned r = atomicAdd(&off[d >> 6], 1u);
        tg[r] = ((unsigned)(d & 63) << 15) | (unsigned)s;
    }
}

// ---------- CSR phase D ----------
__global__ __launch_bounds__(256) void csr_fine(const unsigned* __restrict__ tmp, const unsigned* __restrict__ BB,
                                                int* __restrict__ row, int* __restrict__ csr_src) {
    int blk = blockIdx.x;
    int g = blk / NBUCK, b = blk - g * NBUCK;
    unsigned lo = BB[(size_t)g * (NBUCK + 1) + b];
    unsigned hi = BB[(size_t)g * (NBUCK + 1) + b + 1];
    __shared__ unsigned cnt[64];
    __shared__ unsigned pos[64];
    if (threadIdx.x < 64) cnt[threadIdx.x] = 0;
    __syncthreads();
    const unsigned* tg = tmp + (size_t)g * E_EDGES;
    for (unsigned i = lo + threadIdx.x; i < hi; i += 256)
        atomicAdd(&cnt[(tg[i] >> 15) & 63], 1u);
    __syncthreads();
    if (threadIdx.x < 64) {
        unsigned v = cnt[threadIdx.x];
        unsigned inc = v;
#pragma unroll
        for (int o = 1; o < 64; o <<= 1) {
            unsigned u = __shfl_up(inc, o);
            if ((int)threadIdx.x >= o) inc += u;
        }
        unsigned e = inc - v;
        pos[threadIdx.x] = lo + e;
        int n = b * 64 + (int)threadIdx.x;
        if (n <= N_NODES) row[(size_t)g * (N_NODES + 1) + n] = (int)(lo + e);
    }
    __syncthreads();
    for (unsigned i = lo + threadIdx.x; i < hi; i += 256) {
        unsigned v = tg[i];
        unsigned r = atomicAdd(&pos[(v >> 15) & 63], 1u);
        csr_src[(size_t)g * E_EDGES + r] = (int)(v & 0x7fffu);
    }
}

// ---------- W prep: transpose + bf16 hi/lo split. Layout: [plane][type][col][K] ----------
__global__ void wprep_kernel(const float* __restrict__ pW1, const float* __restrict__ sW1,
                             const float* __restrict__ pW2, const float* __restrict__ sW2,
                             short* __restrict__ w1t, short* __restrict__ w2t) {
    constexpr int N1 = 2 * HID * IN_DIM;
    constexpr int N2 = 2 * F_OUT * HID;
    int idx = blockIdx.x * 256 + threadIdx.x;
    if (idx < N1) {
        int t = idx / (HID * IN_DIM);
        int r = idx % (HID * IN_DIM);
        int col = r / IN_DIM, k = r % IN_DIM;
        const float* W = t ? sW1 : pW1;
        float v = W[(size_t)k * HID + col];
        uint32_t hi = f2bf(v);
        float fhi = __builtin_bit_cast(float, hi << 16);
        w1t[idx]      = (short)hi;
        w1t[idx + N1] = (short)f2bf(v - fhi);
    } else if (idx < N1 + N2) {
        int j = idx - N1;
        int t = j / (F_OUT * HID);
        int r = j % (F_OUT * HID);
        int col = r / HID, k = r % HID;
        const float* W = t ? sW2 : pW2;
        float v = W[(size_t)k * F_OUT + col];
        uint32_t hi = f2bf(v);
        float fhi = __builtin_bit_cast(float, hi << 16);
        w2t[j]      = (short)hi;
        w2t[j + N2] = (short)f2bf(v - fhi);
    }
}

// ---------- MFMA GEMM: out_bf16[g][n][NCOL] = X[g][n][K] @ W_g ; A=bf16(X), B=W_hi+W_lo ----------
template<int KDIM, int NCOL, bool CVT>
__global__ __launch_bounds__(256) void mm_mfma(const void* __restrict__ pXv, const void* __restrict__ sXv,
                                               const short* __restrict__ wt,   // [2 planes][2 types][NCOL][KDIM]
                                               uint16_t* __restrict__ outb) {
    constexpr int BPG = (N_NODES + 127) / 128;   // 157
    constexpr int NT = NCOL / 16;
    int g = blockIdx.x / BPG;
    int brow = (blockIdx.x % BPG) * 128;
    const short* wtg = wt + (g ? (size_t)NCOL * KDIM : 0);   // hi plane; lo at +2*NCOL*KDIM
    __shared__ __align__(16) short As[128 * 40];
    __shared__ __align__(16) short Bh[NCOL * 40];
    __shared__ __align__(16) short Bl[NCOL * 40];
    int tid = threadIdx.x;
    int w = tid >> 6, l = tid & 63;
    int lr = l & 15, kq = l >> 4;
    f32x4 acc[2][NT] = {};
    for (int k0 = 0; k0 < KDIM; k0 += 32) {
        if (CVT) {
            const float* X = (g == 0) ? (const float*)pXv
                                      : (const float*)sXv + (size_t)(g - 1) * N_NODES * KDIM;
#pragma unroll
            for (int i = 0; i < 4; ++i) {                 // 128 rows x 8 float4 = 1024 transactions
                int v = tid + i * 256;
                int r = v >> 3, q = v & 7;
                float4 xv = make_float4(0.f, 0.f, 0.f, 0.f);
                if (brow + r < N_NODES)
                    xv = *(const float4*)(X + (size_t)(brow + r) * KDIM + k0 + q * 4);
                uint2 pkd; pkd.x = pk2(xv.x, xv.y); pkd.y = pk2(xv.z, xv.w);
                *(uint2*)(As + r * 40 + q * 4) = pkd;
            }
        } else {
            const uint16_t* X = (g == 0) ? (const uint16_t*)pXv
                                         : (const uint16_t*)sXv + (size_t)(g - 1) * N_NODES * KDIM;
#pragma unroll
            for (int i = 0; i < 2; ++i) {                 // 128 rows x 4 uint4 = 512 transactions
                int v = tid + i * 256;
                int r = v >> 2, q = v & 3;
                uint4 xv = make_uint4(0u, 0u, 0u, 0u);
                if (brow + r < N_NODES)
                    xv = *(const uint4*)(X + (size_t)(brow + r) * KDIM + k0 + q * 8);
                *(uint4*)(As + r * 40 + q * 8) = xv;
            }
        }
        for (int v = tid; v < NCOL * 4; v += 256) {       // B: NCOL rows x 4 uint4, hi+lo
            int r = v >> 2, q = v & 3;
            const short* srcp = wtg + (size_t)r * KDIM + k0 + q * 8;
            *(uint4*)(Bh + r * 40 + q * 8) = *(const uint4*)srcp;
            *(uint4*)(Bl + r * 40 + q * 8) = *(const uint4*)(srcp + (size_t)2 * NCOL * KDIM);
        }
        __syncthreads();
        short8 a0 = *(const short8*)(As + (w * 32 + lr) * 40 + kq * 8);
        short8 a1 = *(const short8*)(As + (w * 32 + 16 + lr) * 40 + kq * 8);
#pragma unroll
        for (int ct = 0; ct < NT; ++ct) {
            short8 bh = *(const short8*)(Bh + (ct * 16 + lr) * 40 + kq * 8);
            short8 bl = *(const short8*)(Bl + (ct * 16 + lr) * 40 + kq * 8);
            acc[0][ct] = __builtin_amdgcn_mfma_f32_16x16x32_bf16(a0, bh, acc[0][ct], 0, 0, 0);
            acc[0][ct] = __builtin_amdgcn_mfma_f32_16x16x32_bf16(a0, bl, acc[0][ct], 0, 0, 0);
            acc[1][ct] = __builtin_amdgcn_mfma_f32_16x16x32_bf16(a1, bh, acc[1][ct], 0, 0, 0);
            acc[1][ct] = __builtin_amdgcn_mfma_f32_16x16x32_bf16(a1, bl, acc[1][ct], 0, 0, 0);
        }
        __syncthreads();
    }
#pragma unroll
    for (int rt = 0; rt < 2; ++rt) {
#pragma unroll
        for (int ct = 0; ct < NT; ++ct) {
#pragma unroll
            for (int i = 0; i < 4; ++i) {
                int node = brow + w * 32 + rt * 16 + kq * 4 + i;
                if (node < N_NODES)
                    outb[((size_t)g * N_NODES + node) * NCOL + ct * 16 + lr] = (uint16_t)f2bf(acc[rt][ct][i]);
            }
        }
    }
}

// ---------- per-node attention scalars from bf16 h ----------
__global__ __launch_bounds__(256) void asad128_kernel(const uint32_t* __restrict__ hb,
                                                      const float* __restrict__ pa, const float* __restrict__ sa,
                                                      float* __restrict__ as_, float* __restrict__ ad_) {
    int wid = (blockIdx.x * 256 + threadIdx.x) >> 6;
    int lane = threadIdx.x & 63;
    if (wid >= G_TOT * N_NODES) return;
    int g = wid / N_NODES;
    const float* a = (g == 0) ? pa : sa;
    uint32_t hv = hb[(size_t)wid * 64 + lane];
    float h0 = bflo(hv), h1 = bfhi(hv);
    float2 a_s = *(const float2*)(a + 2 * lane);
    float2 a_d = *(const float2*)(a + 128 + 2 * lane);
    float s = h0 * a_s.x + h1 * a_s.y;
    float d = h0 * a_d.x + h1 * a_d.y;
#pragma unroll
    for (int off = 32; off; off >>= 1) { s += __shfl_xor(s, off); d += __shfl_xor(d, off); }
    if (lane == 0) { as_[wid] = s; ad_[wid] = d; }
}

__global__ __launch_bounds__(256) void asad64_kernel(const uint32_t* __restrict__ hb,
                                                     const float* __restrict__ pa, const float* __restrict__ sa,
                                                     float* __restrict__ as_, float* __restrict__ ad_) {
    int wid = (blockIdx.x * 256 + threadIdx.x) >> 6;
    int lane = threadIdx.x & 63;
    if (wid >= G_TOT * N_NODES) return;
    int g = wid / N_NODES;
    const float* a = (g == 0) ? pa : sa;
    const uint16_t* hr = (const uint16_t*)(hb + (size_t)wid * 32);
    float h = __builtin_bit_cast(float, (uint32_t)hr[lane] << 16);
    float s = h * a[lane];
    float d = h * a[64 + lane];
#pragma unroll
    for (int off = 32; off; off >>= 1) { s += __shfl_xor(s, off); d += __shfl_xor(d, off); }
    if (lane == 0) { as_[wid] = s; ad_[wid] = d; }
}

// ---------- GAT aggregation, F=128: online softmax + 2-deep pipelined uint4 gather; bf16 out ----------
__global__ __launch_bounds__(256) void agg128_kernel(const uint32_t* __restrict__ hb,
                                                     const float* __restrict__ as_, const float* __restrict__ ad_,
                                                     const int* __restrict__ row, const int* __restrict__ csr_src,
                                                     const float* __restrict__ pb, const float* __restrict__ sb,
                                                     uint32_t* __restrict__ h1p) {
    int node = blockIdx.x * 4 + (threadIdx.x >> 6);
    int g = node / N_NODES;
    int n = node - g * N_NODES;
    int lane = threadIdx.x & 63;
    int start = row[(size_t)g * (N_NODES + 1) + n];
    int end   = row[(size_t)g * (N_NODES + 1) + n + 1];
    const int* src = csr_src + (size_t)g * E_EDGES;
    const float* asg = as_ + (size_t)g * N_NODES;
    const uint32_t* hg = hb + (size_t)g * N_NODES * 64;
    float ad_d = ad_[node];
    float e_self = leaky(asg[n] + ad_d);
    int grp = lane >> 4;                 // edge slot within quad
    int f = lane & 15;                   // uint4 slice: feats f*8 .. f*8+7
    const uint32_t* hf = hg + f * 4;
    float m = e_self, denomp = 0.f;
    float a0 = 0.f, a1 = 0.f, a2 = 0.f, a3 = 0.f, a4 = 0.f, a5 = 0.f, a6 = 0.f, a7 = 0.f;
    for (int j0 = start; j0 < end; j0 += 64) {
        int j = j0 + lane;
        float e = -3.0e38f; int s0 = 0;
        if (j < end) { s0 = src[j]; e = leaky(asg[s0] + ad_d); }
        float cmax = e;
#pragma unroll
        for (int off = 32; off; off >>= 1) cmax = fmaxf(cmax, __shfl_xor(cmax, off));
        if (cmax > m) {                  // wave-uniform rescale (rare)
            float sc = __expf(m - cmax);
            denomp *= sc;
            a0 *= sc; a1 *= sc; a2 *= sc; a3 *= sc; a4 *= sc; a5 *= sc; a6 *= sc; a7 *= sc;
            m = cmax;
        }
        float w0 = (j < end) ? __expf(e - m) : 0.f;
        denomp += w0;
        int cnt = min(64, end - j0);
        // 8 edges per superstep: batch shfls, 2 gathers in flight, then FMA.
        // (4-deep regressed in R10: occupancy cliff. 2-deep = +8 VGPR only.)
        // Tail lanes have w0=0, s0=0 -> harmless row-0 loads with zero weight.
        for (int t = 0; t < cnt; t += 8) {
            float w_[2]; int s_[2];
#pragma unroll
            for (int u = 0; u < 2; ++u) {
                int tt = t + u * 4 + grp;           // <= 63 always
                w_[u] = __shfl(w0, tt);
                s_[u] = __shfl(s0, tt);
            }
            uint4 hv_[2];
#pragma unroll
            for (int u = 0; u < 2; ++u)
                hv_[u] = *(const uint4*)(hf + (size_t)s_[u] * 64);
#pragma unroll
            for (int u = 0; u < 2; ++u) {
                float w = w_[u]; uint4 hv = hv_[u];
                a0 += w * bflo(hv.x); a1 += w * bfhi(hv.x);
                a2 += w * bflo(hv.y); a3 += w * bfhi(hv.y);
                a4 += w * bflo(hv.z); a5 += w * bfhi(hv.z);
                a6 += w * bflo(hv.w); a7 += w * bfhi(hv.w);
            }
        }
    }
#pragma unroll
    for (int off = 32; off; off >>= 1) denomp += __shfl_xor(denomp, off);
#pragma unroll
    for (int off = 16; off <= 32; off <<= 1) {
        a0 += __shfl_xor(a0, off); a1 += __shfl_xor(a1, off);
        a2 += __shfl_xor(a2, off); a3 += __shfl_xor(a3, off);
        a4 += __shfl_xor(a4, off); a5 += __shfl_xor(a5, off);
        a6 += __shfl_xor(a6, off); a7 += __shfl_xor(a7, off);
    }
    if (lane < 16) {
        float wself = __expf(e_self - m);
        float inv = 1.f / (denomp + wself + 1e-16f);
        uint4 hv = *(const uint4*)(hg + (size_t)n * 64 + lane * 4);
        const float* b = (g == 0) ? pb : sb;
        float4 b0 = *(const float4*)(b + lane * 8);
        float4 b1 = *(const float4*)(b + lane * 8 + 4);
        float o0 = fmaxf((a0 + wself * bflo(hv.x)) * inv + b0.x, 0.f);
        float o1 = fmaxf((a1 + wself * bfhi(hv.x)) * inv + b0.y, 0.f);
        float o2 = fmaxf((a2 + wself * bflo(hv.y)) * inv + b0.z, 0.f);
        float o3 = fmaxf((a3 + wself * bfhi(hv.y)) * inv + b0.w, 0.f);
        float o4 = fmaxf((a4 + wself * bflo(hv.z)) * inv + b1.x, 0.f);
        float o5 = fmaxf((a5 + wself * bfhi(hv.z)) * inv + b1.y, 0.f);
        float o6 = fmaxf((a6 + wself * bflo(hv.w)) * inv + b1.z, 0.f);
        float o7 = fmaxf((a7 + wself * bfhi(hv.w)) * inv + b1.w, 0.f);
        uint4 o; o.x = pk2(o0, o1); o.y = pk2(o2, o3); o.z = pk2(o4, o5); o.w = pk2(o6, o7);
        *(uint4*)(h1p + (size_t)node * 64 + lane * 4) = o;
    }
}

// ---------- GAT aggregation, F=64: online softmax + 4-deep pipelined uint2 gather; fp32 out ----------
__global__ __launch_bounds__(256) void agg64_kernel(const uint32_t* __restrict__ hb,
                                                    const float* __restrict__ as_, const float* __restrict__ ad_,
                                                    const int* __restrict__ row, const int* __restrict__ csr_src,
                                                    const float* __restrict__ pb, const float* __restrict__ sb,
                                                    float* __restrict__ outp) {
    int node = blockIdx.x * 4 + (threadIdx.x >> 6);
    int g = node / N_NODES;
    int n = node - g * N_NODES;
    int lane = threadIdx.x & 63;
    int start = row[(size_t)g * (N_NODES + 1) + n];
    int end   = row[(size_t)g * (N_NODES + 1) + n + 1];
    const int* src = csr_src + (size_t)g * E_EDGES;
    const float* asg = as_ + (size_t)g * N_NODES;
    const uint32_t* hg = hb + (size_t)g * N_NODES * 32;
    float ad_d = ad_[node];
    float e_self = leaky(asg[n] + ad_d);
    int grp = lane >> 4;
    int f = lane & 15;                   // uint2 slice: feats f*4 .. f*4+3
    const uint32_t* hf = hg + f * 2;
    float m = e_self, denomp = 0.f;
    float a0 = 0.f, a1 = 0.f, a2 = 0.f, a3 = 0.f;
    for (int j0 = start; j0 < end; j0 += 64) {
        int j = j0 + lane;
        float e = -3.0e38f; int s0 = 0;
        if (j < end) { s0 = src[j]; e = leaky(asg[s0] + ad_d); }
        float cmax = e;
#pragma unroll
        for (int off = 32; off; off >>= 1) cmax = fmaxf(cmax, __shfl_xor(cmax, off));
        if (cmax > m) {
            float sc = __expf(m - cmax);
            denomp *= sc;
            a0 *= sc; a1 *= sc; a2 *= sc; a3 *= sc;
            m = cmax;
        }
        float w0 = (j < end) ? __expf(e - m) : 0.f;
        denomp += w0;
        int cnt = min(64, end - j0);
        for (int t = 0; t < cnt; t += 16) {
            float w_[4]; int s_[4];
#pragma unroll
            for (int u = 0; u < 4; ++u) {
                int tt = t + u * 4 + grp;
                w_[u] = __shfl(w0, tt);
                s_[u] = __shfl(s0, tt);
            }
            uint2 hv_[4];
#pragma unroll
            for (int u = 0; u < 4; ++u)
                hv_[u] = *(const uint2*)(hf + (size_t)s_[u] * 32);
#pragma unroll
            for (int u = 0; u < 4; ++u) {
                float w = w_[u]; uint2 hv = hv_[u];
                a0 += w * bflo(hv.x); a1 += w * bfhi(hv.x);
                a2 += w * bflo(hv.y); a3 += w * bfhi(hv.y);
            }
        }
    }
#pragma unroll
    for (int off = 32; off; off >>= 1) denomp += __shfl_xor(denomp, off);
#pragma unroll
    for (int off = 16; off <= 32; off <<= 1) {
        a0 += __shfl_xor(a0, off); a1 += __shfl_xor(a1, off);
        a2 += __shfl_xor(a2, off); a3 += __shfl_xor(a3, off);
    }
    if (lane < 16) {
        float wself = __expf(e_self - m);
        float inv = 1.f / (denomp + wself + 1e-16f);
        uint2 hv = *(const uint2*)(hg + (size_t)n * 32 + lane * 2);
        const float* b = (g == 0) ? pb : sb;
        float4 bv = *(const float4*)(b + lane * 4);
        float4 o;
        o.x = (a0 + wself * bflo(hv.x)) * inv + bv.x;
        o.y = (a1 + wself * bfhi(hv.x)) * inv + bv.y;
        o.z = (a2 + wself * bflo(hv.y)) * inv + bv.z;
        o.w = (a3 + wself * bfhi(hv.y)) * inv + bv.w;
        *(float4*)(outp + (size_t)node * 64 + lane * 4) = o;
    }
}

// ---------- mean over nodes -> emb[g][64] ----------
__global__ __launch_bounds__(256) void mean_kernel(const float* __restrict__ out2, float* __restrict__ emb) {
    constexpr int CH = 32;
    int g = blockIdx.x / CH, chunk = blockIdx.x % CH;
    int f = threadIdx.x & 63, sub = threadIdx.x >> 6;
    float acc = 0.f;
    for (int n = chunk * 4 + sub; n < N_NODES; n += CH * 4)
        acc += out2[((size_t)g * N_NODES + n) * 64 + f];
    __shared__ float red[256];
    red[threadIdx.x] = acc;
    __syncthreads();
    if (sub == 0) {
        float s = red[f] + red[64 + f] + red[128 + f] + red[192 + f];
        atomicAdd(&emb[g * 64 + f], s * (1.f / N_NODES));
    }
}

// ---------- cosine-similarity head ----------
__global__ __launch_bounds__(64) void final_kernel(const float* __restrict__ emb,
                                                   const float* __restrict__ temp, float* __restrict__ out) {
    int lane = threadIdx.x;
    float pe = emb[lane];
    float pp = pe * pe;
#pragma unroll
    for (int off = 32; off; off >>= 1) pp += __shfl_xor(pp, off);
    float t = temp[0];
    float pn = sqrtf(pp);
    for (int s_i = 0; s_i < S_STORIES; ++s_i) {
        float se = emb[(1 + s_i) * 64 + lane];
        float ss = se * se;
        float dt = se * pe;
#pragma unroll
        for (int off = 32; off; off >>= 1) { ss += __shfl_xor(ss, off); dt += __shfl_xor(dt, off); }
        if (lane == 0) out[s_i] = dt / (sqrtf(ss) * pn * t);
    }
}

extern "C" void kernel_launch(void* const* d_in, const int* in_sizes, int n_in,
                              void* d_out, int out_size, void* d_ws, size_t ws_size,
                              hipStream_t stream) {
    const float* persona_x = (const float*)d_in[0];
    const int*   pei       = (const int*)d_in[1];
    const float* story_x   = (const float*)d_in[2];
    const int*   sei       = (const int*)d_in[3];
    const float* p_W1 = (const float*)d_in[4];
    const float* p_a1 = (const float*)d_in[5];
    const float* p_b1 = (const float*)d_in[6];
    const float* p_W2 = (const float*)d_in[7];
    const float* p_a2 = (const float*)d_in[8];
    const float* p_b2 = (const float*)d_in[9];
    const float* s_W1 = (const float*)d_in[10];
    const float* s_a1 = (const float*)d_in[11];
    const float* s_b1 = (const float*)d_in[12];
    const float* s_W2 = (const float*)d_in[13];
    const float* s_a2 = (const float*)d_in[14];
    const float* s_b2 = (const float*)d_in[15];
    const float* temp = (const float*)d_in[16];
    float* out = (float*)d_out;

    char* ws = (char*)d_ws;
    size_t off = 0;
    auto alloc = [&](size_t bytes) { char* p = ws + off; off += (bytes + 255) & ~(size_t)255; return p; };
    uint32_t* hb1  = (uint32_t*)alloc((size_t)G_TOT * N_NODES * 64 * 4);   // bf16 h1; CSR tmp + out2 alias
    uint32_t* h1p  = (uint32_t*)alloc((size_t)G_TOT * N_NODES * 64 * 4);   // bf16 h1'; CSR C/BB alias
    uint32_t* hb2  = (uint32_t*)alloc((size_t)G_TOT * N_NODES * 32 * 4);   // bf16 h2
    float* as_     = (float*)alloc((size_t)G_TOT * N_NODES * 4);
    float* ad_     = (float*)alloc((size_t)G_TOT * N_NODES * 4);
    int*   csr_row = (int*)  alloc((size_t)G_TOT * (N_NODES + 1) * 4);
    int*   csr_src = (int*)  alloc((size_t)G_TOT * E_EDGES * 4);
    float* emb     = (float*)alloc((size_t)G_TOT * 64 * 4);
    short* w1t     = (short*)alloc((size_t)2 * 2 * HID * IN_DIM * 2);      // [plane][type][col][K]
    short* w2t     = (short*)alloc((size_t)2 * 2 * F_OUT * HID * 2);
    if (off > ws_size) {
        fprintf(stderr, "kernel_launch: ws too small: need %zu have %zu\n", off, ws_size);
        return;
    }
    unsigned* tmp = (unsigned*)hb1;                                    // 84.5 MB <= 169 MB, dead before mm1
    unsigned* C   = (unsigned*)h1p;                                    // 3.3 MB, dead before agg128
    unsigned* BB  = (unsigned*)h1p + (size_t)G_TOT * NB * NBUCK;
    float* out2   = (float*)hb1;                                       // hb1 dead after agg128

    constexpr int BPG = (N_NODES + 127) / 128;   // 157
    const int NODE_BLOCKS = G_TOT * N_NODES / 4; // 165000, exact

    // CSR build + weight prep
    zero_kernel<<<(G_TOT * 64 + 255) / 256, 256, 0, stream>>>(emb, (size_t)G_TOT * 64);
    wprep_kernel<<<(2 * HID * IN_DIM + 2 * F_OUT * HID + 255) / 256, 256, 0, stream>>>(p_W1, s_W1, p_W2, s_W2, w1t, w2t);
    csr_count <<<G_TOT * NB, 256, 0, stream>>>(pei, sei, C);
    csr_scan  <<<G_TOT, 512, 0, stream>>>(C, BB);
    csr_bucket<<<G_TOT * NB, 256, 0, stream>>>(pei, sei, C, tmp);
    csr_fine  <<<G_TOT * NBUCK, 256, 0, stream>>>(tmp, BB, csr_row, csr_src);

    // Layer 1
    mm_mfma<IN_DIM, HID, true><<<G_TOT * BPG, 256, 0, stream>>>(persona_x, story_x, w1t, (uint16_t*)hb1);
    asad128_kernel<<<(G_TOT * N_NODES + 3) / 4, 256, 0, stream>>>(hb1, p_a1, s_a1, as_, ad_);
    agg128_kernel<<<NODE_BLOCKS, 256, 0, stream>>>(hb1, as_, ad_, csr_row, csr_src, p_b1, s_b1, h1p);

    // Layer 2 (A operand already bf16)
    const uint16_t* h1p16 = (const uint16_t*)h1p;
    mm_mfma<HID, F_OUT, false><<<G_TOT * BPG, 256, 0, stream>>>(h1p16, h1p16 + (size_t)N_NODES * HID, w2t, (uint16_t*)hb2);
    asad64_kernel<<<(G_TOT * N_NODES + 3) / 4, 256, 0, stream>>>(hb2, p_a2, s_a2, as_, ad_);
    agg64_kernel<<<NODE_BLOCKS, 256, 0, stream>>>(hb2, as_, ad_, csr_row, csr_src, p_b2, s_b2, out2);

    // Readout
    mean_kernel<<<G_TOT * 32, 256, 0, stream>>>(out2, emb);
    final_kernel<<<1, 64, 0, stream>>>(emb, temp, out);
}